// Round 1
// baseline (432.594 us; speedup 1.0000x reference)
//
#include <hip/hip_runtime.h>

// result = 0.25*sum(M) - 0.5*[ sum_{i<j} M_ij s_i s_j + sum_i M_ii s_i ]
//
// R4: persistent rows-per-block. Old structure = 8192 tiny blocks, each with
// a serial tail (reduce + sync + retire + state re-fetch) between 32 KiB
// streams -> load queue drained at every block boundary -> ~1.7 TB/s.
// New structure: 1024 blocks x 8 consecutive rows, state held in registers
// across rows, explicit mA/mB double buffer so next row's loads are in
// flight during current row's compute, ONE reduction per block.
// Per-thread fold: acc += 0.25*accA_row + p_row*accQ_row (pure sum -> legal).

static constexpr int N_DIM  = 8192;
static constexpr int VPR    = N_DIM / 4;     // 2048 float4 per row
static constexpr int BLOCK  = 256;
static constexpr int ITERS  = VPR / BLOCK;   // 8 float4 per thread per row
static constexpr int GRID   = 1024;          // blocks
static constexpr int RPB    = N_DIM / GRID;  // 8 consecutive rows per block (even!)
static constexpr int FBLOCK = 1024;

__device__ __forceinline__ float row_term(
    const float4 (&m)[ITERS], const float4 (&s)[ITERS],
    const int tid, const int row, const float p)
{
    const int d = row >> 2;                  // diagonal's vec4 index
    float accA = 0.0f, q0 = 0.0f, q1 = 0.0f;
#pragma unroll
    for (int k = 0; k < ITERS; ++k) {
        const int    v  = tid + (k << 8);
        const float4 mm = m[k];
        const float4 sj = s[k];
        accA += (mm.x + mm.y) + (mm.z + mm.w);
        if (v > d) {                         // wave-uniform except 1 wave
            q0 = fmaf(mm.x, sj.x, q0);
            q1 = fmaf(mm.y, sj.y, q1);
            q0 = fmaf(mm.z, sj.z, q0);
            q1 = fmaf(mm.w, sj.w, q1);
        } else if (v == d) {                 // exactly one thread
            const int j0 = v << 2;
            float w;
            w = (j0 + 0 > row) ? sj.x : ((j0 + 0 == row) ? 1.0f : 0.0f);
            q0 = fmaf(mm.x, w, q0);
            w = (j0 + 1 > row) ? sj.y : ((j0 + 1 == row) ? 1.0f : 0.0f);
            q1 = fmaf(mm.y, w, q1);
            w = (j0 + 2 > row) ? sj.z : ((j0 + 2 == row) ? 1.0f : 0.0f);
            q0 = fmaf(mm.z, w, q0);
            w = (j0 + 3 > row) ? sj.w : ((j0 + 3 == row) ? 1.0f : 0.0f);
            q1 = fmaf(mm.w, w, q1);
        }
    }
    return fmaf(0.25f, accA, p * (q0 + q1));
}

__global__ __launch_bounds__(BLOCK, 4) void ising_rows_kernel(
    const float4* __restrict__ mtx4,
    const float*  __restrict__ state,
    float*        __restrict__ partial)
{
    const int tid = threadIdx.x;
    const float4* __restrict__ s4 = (const float4*)state;

    // State slice once per block: 8 float4 = 32 VGPR, reused for all 8 rows.
    float4 s[ITERS];
#pragma unroll
    for (int k = 0; k < ITERS; ++k)
        s[k] = s4[tid + (k << 8)];

    const int row0 = blockIdx.x * RPB;       // 8 consecutive rows: 256 KiB stream
    const float4* __restrict__ base = mtx4 + (size_t)row0 * VPR;

    // Prologue: row 0 into mA.
    float4 mA[ITERS], mB[ITERS];
#pragma unroll
    for (int k = 0; k < ITERS; ++k)
        mA[k] = base[tid + (k << 8)];

    float acc = 0.0f;

    for (int g = 0; g < RPB; g += 2) {
        // Prefetch row g+1 into mB BEFORE computing row g: queue never drains.
#pragma unroll
        for (int k = 0; k < ITERS; ++k)
            mB[k] = base[(g + 1) * VPR + tid + (k << 8)];

        {
            const int   row = row0 + g;
            const float p   = -0.5f * state[row];   // wave-uniform s_load
            acc += row_term(mA, s, tid, row, p);
        }

        if (g + 2 < RPB) {
#pragma unroll
            for (int k = 0; k < ITERS; ++k)
                mA[k] = base[(g + 2) * VPR + tid + (k << 8)];
        }

        {
            const int   row = row0 + g + 1;
            const float p   = -0.5f * state[row];
            acc += row_term(mB, s, tid, row, p);
        }
    }

    // ONE reduction per block (was: per row).
    for (int off = 32; off > 0; off >>= 1)
        acc += __shfl_down(acc, off, 64);

    __shared__ float lds[BLOCK / 64];
    const int lane = tid & 63;
    const int wave = tid >> 6;
    if (lane == 0) lds[wave] = acc;
    __syncthreads();
    if (tid == 0)
        partial[blockIdx.x] = (lds[0] + lds[1]) + (lds[2] + lds[3]);
}

__global__ __launch_bounds__(FBLOCK) void ising_final_kernel(
    const float* __restrict__ partial,
    float*       __restrict__ out)
{
    float acc = partial[threadIdx.x];        // GRID == FBLOCK == 1024

    for (int off = 32; off > 0; off >>= 1)
        acc += __shfl_down(acc, off, 64);

    __shared__ float lds[FBLOCK / 64];
    const int lane = threadIdx.x & 63;
    const int wave = threadIdx.x >> 6;
    if (lane == 0) lds[wave] = acc;
    __syncthreads();
    if (threadIdx.x == 0) {
        float sum = 0.0f;
#pragma unroll
        for (int w = 0; w < FBLOCK / 64; ++w) sum += lds[w];
        out[0] = sum;
    }
}

extern "C" void kernel_launch(void* const* d_in, const int* in_sizes, int n_in,
                              void* d_out, int out_size, void* d_ws, size_t ws_size,
                              hipStream_t stream) {
    const float* mtx   = (const float*)d_in[0];   // [8192*8192] fp32
    const float* state = (const float*)d_in[1];   // [8192] fp32
    float* out     = (float*)d_out;
    float* partial = (float*)d_ws;                // 1024 floats, fully overwritten

    ising_rows_kernel<<<GRID, BLOCK, 0, stream>>>((const float4*)mtx, state, partial);
    ising_final_kernel<<<1, FBLOCK, 0, stream>>>(partial, out);
}

// Round 2
// 357.058 us; speedup vs baseline: 1.2116x; 1.2116x over previous
//
#include <hip/hip_runtime.h>

// result = 0.25*sum(M) - 0.5*[ sum_{i<j} M_ij s_i s_j + sum_i M_ii s_i ]
//
// R5: persistent rows-per-block (1024 blocks x 8 rows), state slice in
// registers, ONE reduction per block -- but NO double buffer and NO
// launch-bounds occupancy hint. R4's mA/mB + s arrays (96 floats) against a
// 64-VGPR allocation spilled to scratch: WRITE_SIZE showed 194 MB of spill
// writes (vs 4 KB of real output), burning ~40% of HBM BW. Per-row m[8]
// (32 VGPR) + s[8] (32 VGPR) + misc fits ~128 VGPR -> no scratch; latency
// is hidden by TLP (16 waves/CU x 8 outstanding dwordx4 each >> 9 KB
// BW*latency product). #pragma unroll 1 on the row loop prevents the
// compiler from re-creating multi-row liveness.

static constexpr int N_DIM  = 8192;
static constexpr int VPR    = N_DIM / 4;     // 2048 float4 per row
static constexpr int BLOCK  = 256;
static constexpr int ITERS  = VPR / BLOCK;   // 8 float4 per thread per row
static constexpr int GRID   = 1024;          // 4 blocks/CU, one generation
static constexpr int RPB    = N_DIM / GRID;  // 8 consecutive rows per block
static constexpr int FBLOCK = 1024;

__global__ __launch_bounds__(BLOCK) void ising_rows_kernel(
    const float4* __restrict__ mtx4,
    const float*  __restrict__ state,
    float*        __restrict__ partial)
{
    const int tid = threadIdx.x;
    const float4* __restrict__ s4 = (const float4*)state;

    // State slice once per block: 8 float4 = 32 VGPR, reused for all 8 rows.
    float4 s[ITERS];
#pragma unroll
    for (int k = 0; k < ITERS; ++k)
        s[k] = s4[tid + (k << 8)];

    const int row0 = blockIdx.x * RPB;       // 8 consecutive rows: 256 KiB stream
    const float4* __restrict__ base = mtx4 + (size_t)row0 * VPR;

    float acc = 0.0f;

#pragma unroll 1
    for (int g = 0; g < RPB; ++g) {
        const int   row = row0 + g;
        const int   d   = row >> 2;              // diagonal's vec4 index
        const float p   = -0.5f * state[row];    // wave-uniform scalar load

        // 8 independent dwordx4 issued back-to-back; compiler interleaves
        // fine-grained vmcnt waits with the consuming FMAs below.
        float4 m[ITERS];
#pragma unroll
        for (int k = 0; k < ITERS; ++k)
            m[k] = base[(size_t)g * VPR + tid + (k << 8)];

        float accA = 0.0f, q0 = 0.0f, q1 = 0.0f;
#pragma unroll
        for (int k = 0; k < ITERS; ++k) {
            const int    v  = tid + (k << 8);
            const float4 mm = m[k];
            const float4 sj = s[k];
            accA += (mm.x + mm.y) + (mm.z + mm.w);
            if (v > d) {                         // wave-uniform except 1 wave
                q0 = fmaf(mm.x, sj.x, q0);
                q1 = fmaf(mm.y, sj.y, q1);
                q0 = fmaf(mm.z, sj.z, q0);
                q1 = fmaf(mm.w, sj.w, q1);
            } else if (v == d) {                 // exactly one thread
                const int j0 = v << 2;
                float w;
                w = (j0 + 0 > row) ? sj.x : ((j0 + 0 == row) ? 1.0f : 0.0f);
                q0 = fmaf(mm.x, w, q0);
                w = (j0 + 1 > row) ? sj.y : ((j0 + 1 == row) ? 1.0f : 0.0f);
                q1 = fmaf(mm.y, w, q1);
                w = (j0 + 2 > row) ? sj.z : ((j0 + 2 == row) ? 1.0f : 0.0f);
                q0 = fmaf(mm.z, w, q0);
                w = (j0 + 3 > row) ? sj.w : ((j0 + 3 == row) ? 1.0f : 0.0f);
                q1 = fmaf(mm.w, w, q1);
            }
        }
        acc = fmaf(0.25f, accA, fmaf(p, q0 + q1, acc));
    }

    // ONE reduction per block (amortized over 8 rows).
    for (int off = 32; off > 0; off >>= 1)
        acc += __shfl_down(acc, off, 64);

    __shared__ float lds[BLOCK / 64];
    const int lane = tid & 63;
    const int wave = tid >> 6;
    if (lane == 0) lds[wave] = acc;
    __syncthreads();
    if (tid == 0)
        partial[blockIdx.x] = (lds[0] + lds[1]) + (lds[2] + lds[3]);
}

__global__ __launch_bounds__(FBLOCK) void ising_final_kernel(
    const float* __restrict__ partial,
    float*       __restrict__ out)
{
    float acc = partial[threadIdx.x];        // GRID == FBLOCK == 1024

    for (int off = 32; off > 0; off >>= 1)
        acc += __shfl_down(acc, off, 64);

    __shared__ float lds[FBLOCK / 64];
    const int lane = threadIdx.x & 63;
    const int wave = threadIdx.x >> 6;
    if (lane == 0) lds[wave] = acc;
    __syncthreads();
    if (threadIdx.x == 0) {
        float sum = 0.0f;
#pragma unroll
        for (int w = 0; w < FBLOCK / 64; ++w) sum += lds[w];
        out[0] = sum;
    }
}

extern "C" void kernel_launch(void* const* d_in, const int* in_sizes, int n_in,
                              void* d_out, int out_size, void* d_ws, size_t ws_size,
                              hipStream_t stream) {
    const float* mtx   = (const float*)d_in[0];   // [8192*8192] fp32
    const float* state = (const float*)d_in[1];   // [8192] fp32
    float* out     = (float*)d_out;
    float* partial = (float*)d_ws;                // 1024 floats, fully overwritten

    ising_rows_kernel<<<GRID, BLOCK, 0, stream>>>((const float4*)mtx, state, partial);
    ising_final_kernel<<<1, FBLOCK, 0, stream>>>(partial, out);
}